// Round 2
// baseline (16173.232 us; speedup 1.0000x reference)
//
#include <hip/hip_runtime.h>
#include <math.h>

// ---------------------------------------------------------------------------
// MyRNN persistent kernel, round 2.
//   Phase A: xp = x@Wx^T + bx. Barrier-free: each lane owns (t, row) outputs,
//            full-K dots, Wx rows streamed from L2 (16-lane broadcast),
//            8-timestep register blocking. xp -> global ws.
//   Phase B: 2048 steps. Wave wv owns hidden row 16w+wv; Wh row resident in
//            16 f32x4 VGPRs. Dense flags (int[256]) for the global barrier.
//   Phase C: out = sigmoid(hT @ Wo^T + bo), 8 outputs/WG.
//
// ws layout (32-bit words):
//   [0,    256)   flags[256] (dense; 16 cache lines)
//   [1024, 5120)  hbuf0 (4096 f32) -- h for even-step reads
//   [5120, 9216)  hbuf1 (4096 f32)
//   [9216, ...)   xp [256][2048][16] f32 (32 MiB)
// flags+hbufs memset to 0 every launch (h0 = 0, deterministic replay).
// ---------------------------------------------------------------------------

#define T_STEPS  2048
#define INPUT_N  2048
#define HIDDEN_N 4096
#define NWG      256
#define NTHR     1024

typedef float f32x4 __attribute__((ext_vector_type(4)));

__device__ __forceinline__ float wave_reduce(float v) {
#pragma unroll
  for (int off = 32; off > 0; off >>= 1) v += __shfl_xor(v, off, 64);
  return v;
}

__global__ __launch_bounds__(NTHR, 4) void rnn_persistent(
    const float* __restrict__ x,
    const float* __restrict__ wh_w, const float* __restrict__ wh_b,
    const float* __restrict__ wx_w, const float* __restrict__ wx_b,
    const float* __restrict__ wo_w, const float* __restrict__ wo_b,
    float* __restrict__ out, float* __restrict__ ws) {
  const int w    = blockIdx.x;    // owns hidden rows [16w, 16w+16)
  const int tid  = threadIdx.x;
  const int lane = tid & 63;
  const int wv   = tid >> 6;      // wave 0..15

  int*   flags = (int*)ws;
  float* hbuf0 = ws + 1024;
  float* hbuf1 = ws + 5120;
  float* xp    = ws + 9216;       // [w][t][16]

  __shared__ float s_h[HIDDEN_N];   // 16 KiB

  // ------------------ Phase A: xp (barrier-free, reduce-free) --------------
  {
    const int tq = lane >> 4;        // 0..3
    const int r  = lane & 15;        // row within WG slice
    const float* wrow = wx_w + (size_t)(w * 16 + r) * INPUT_N;
    const float  bA   = wx_b[w * 16 + r];
    for (int g = wv; g < 64; g += 16) {       // 4 groups per wave
      const int t0 = g * 32 + tq;             // t = t0 + 4j, j<8
      f32x4 acc[8];
      const float* xr[8];
#pragma unroll
      for (int j = 0; j < 8; ++j) {
        acc[j] = (f32x4){0.f, 0.f, 0.f, 0.f};
        xr[j]  = x + (size_t)(t0 + 4 * j) * INPUT_N;
      }
      for (int k = 0; k < 512; ++k) {         // 16B granules over K=2048
        f32x4 wq = *(const f32x4*)(wrow + (size_t)k * 4);
#pragma unroll
        for (int j = 0; j < 8; ++j)
          acc[j] += (*(const f32x4*)(xr[j] + (size_t)k * 4)) * wq;
      }
#pragma unroll
      for (int j = 0; j < 8; ++j) {
        float s = acc[j].x + acc[j].y + acc[j].z + acc[j].w + bA;
        xp[((size_t)w * T_STEPS + (t0 + 4 * j)) * 16 + r] = s;
      }
    }
  }
  __syncthreads();   // xp slice complete & visible within WG (same CU)
  if (tid == 0)      // "h_0 (zeros via memset) ready"
    __hip_atomic_store(&flags[w], 1, __ATOMIC_RELAXED,
                       __HIP_MEMORY_SCOPE_AGENT);

  // ------------------ Phase B: the scan ------------------------------------
  // Wave wv owns row R = 16w+wv; its Wh row lives in 16 f32x4 VGPRs.
  const float* whrow = wh_w + (size_t)(w * 16 + wv) * HIDDEN_N + lane * 4;
  f32x4 W[16];
#pragma unroll
  for (int i = 0; i < 16; ++i) W[i] = *(const f32x4*)(whrow + i * 256);
  const float bB = wh_b[w * 16 + wv];

  for (int t = 0; t < T_STEPS; ++t) {
    // prefetch xp[t][wv] early (uniform address per wave; latency hidden)
    const float xpv = xp[((size_t)w * T_STEPS + t) * 16 + wv];

    // 1) wave 0 polls the 256 dense flags until all >= t+1
    if (wv == 0) {
      const int target = t + 1;
      for (;;) {
        int f0 = __hip_atomic_load(&flags[lane], __ATOMIC_RELAXED,
                                   __HIP_MEMORY_SCOPE_AGENT);
        int f1 = __hip_atomic_load(&flags[64 + lane], __ATOMIC_RELAXED,
                                   __HIP_MEMORY_SCOPE_AGENT);
        int f2 = __hip_atomic_load(&flags[128 + lane], __ATOMIC_RELAXED,
                                   __HIP_MEMORY_SCOPE_AGENT);
        int f3 = __hip_atomic_load(&flags[192 + lane], __ATOMIC_RELAXED,
                                   __HIP_MEMORY_SCOPE_AGENT);
        int m01 = f0 < f1 ? f0 : f1;
        int m23 = f2 < f3 ? f2 : f3;
        int m   = m01 < m23 ? m01 : m23;
        if (__all(m >= target)) break;
      }
    }
    __syncthreads();

    // 2) cooperative stage h_t -> LDS (agent loads: straight from L3)
    const float* hsrc = (t & 1) ? hbuf1 : hbuf0;
    float*       hdst = (t & 1) ? hbuf0 : hbuf1;
#pragma unroll
    for (int k = 0; k < 4; ++k)
      s_h[tid + 1024 * k] =
          __hip_atomic_load(&hsrc[tid + 1024 * k], __ATOMIC_RELAXED,
                            __HIP_MEMORY_SCOPE_AGENT);
    __syncthreads();

    // 3) full-row dot from LDS against resident W
    f32x4 a0 = {0.f, 0.f, 0.f, 0.f}, a1 = {0.f, 0.f, 0.f, 0.f};
#pragma unroll
    for (int i = 0; i < 16; i += 2) {
      a0 += (*(const f32x4*)&s_h[lane * 4 + i * 256]) * W[i];
      a1 += (*(const f32x4*)&s_h[lane * 4 + (i + 1) * 256]) * W[i + 1];
    }
    float d = wave_reduce(a0.x + a0.y + a0.z + a0.w +
                          a1.x + a1.y + a1.z + a1.w);

    // 4) per-wave finalize + publish own row
    if (lane == 0) {
      float hn = tanhf(d + bB + xpv);
      __hip_atomic_store(&hdst[w * 16 + wv], hn, __ATOMIC_RELAXED,
                         __HIP_MEMORY_SCOPE_AGENT);
    }
    asm volatile("s_waitcnt vmcnt(0)" ::: "memory");  // own store landed
    __syncthreads();                                   // all 16 rows landed
    if (tid == 0)
      __hip_atomic_store(&flags[w], t + 2, __ATOMIC_RELAXED,
                         __HIP_MEMORY_SCOPE_AGENT);
  }

  // ------------------ Phase C: output --------------------------------------
  if (wv == 0) {
    const int target = T_STEPS + 1;
    for (;;) {
      int f0 = __hip_atomic_load(&flags[lane], __ATOMIC_RELAXED,
                                 __HIP_MEMORY_SCOPE_AGENT);
      int f1 = __hip_atomic_load(&flags[64 + lane], __ATOMIC_RELAXED,
                                 __HIP_MEMORY_SCOPE_AGENT);
      int f2 = __hip_atomic_load(&flags[128 + lane], __ATOMIC_RELAXED,
                                 __HIP_MEMORY_SCOPE_AGENT);
      int f3 = __hip_atomic_load(&flags[192 + lane], __ATOMIC_RELAXED,
                                 __HIP_MEMORY_SCOPE_AGENT);
      int m01 = f0 < f1 ? f0 : f1;
      int m23 = f2 < f3 ? f2 : f3;
      int m   = m01 < m23 ? m01 : m23;
      if (__all(m >= target)) break;
    }
  }
  __syncthreads();
  // h_T is in hbuf0 (t=2047 wrote hdst = hbuf0)
#pragma unroll
  for (int k = 0; k < 4; ++k)
    s_h[tid + 1024 * k] =
        __hip_atomic_load(&hbuf0[tid + 1024 * k], __ATOMIC_RELAXED,
                          __HIP_MEMORY_SCOPE_AGENT);
  __syncthreads();
  if (wv < 8) {
    const int o = w * 8 + wv;
    const float* worow = wo_w + (size_t)o * HIDDEN_N + lane * 4;
    f32x4 acc = {0.f, 0.f, 0.f, 0.f};
#pragma unroll
    for (int k = 0; k < 16; ++k)
      acc += (*(const f32x4*)(worow + k * 256)) *
             (*(const f32x4*)&s_h[lane * 4 + k * 256]);
    float s = wave_reduce(acc.x + acc.y + acc.z + acc.w);
    if (lane == 0) {
      float z = s + wo_b[o];
      out[o] = 1.f / (1.f + expf(-z));
    }
  }
}

extern "C" void kernel_launch(void* const* d_in, const int* in_sizes, int n_in,
                              void* d_out, int out_size, void* d_ws,
                              size_t ws_size, hipStream_t stream) {
  const float* x    = (const float*)d_in[0];
  const float* wh_w = (const float*)d_in[1];
  const float* wh_b = (const float*)d_in[2];
  const float* wx_w = (const float*)d_in[3];
  const float* wx_b = (const float*)d_in[4];
  const float* wo_w = (const float*)d_in[5];
  const float* wo_b = (const float*)d_in[6];
  float* out = (float*)d_out;
  float* ws  = (float*)d_ws;

  // flags + h double-buffer zeroed every call (deterministic replay)
  hipMemsetAsync(d_ws, 0, 9216 * 4, stream);

  hipLaunchKernelGGL(rnn_persistent, dim3(NWG), dim3(NTHR), 0, stream,
                     x, wh_w, wh_b, wx_w, wx_b, wo_w, wo_b, out, ws);
}

// Round 3
// 9874.128 us; speedup vs baseline: 1.6379x; 1.6379x over previous
//
#include <hip/hip_runtime.h>
#include <hip/hip_bf16.h>
#include <math.h>

// ---------------------------------------------------------------------------
// MyRNN persistent kernel, round 3.
//   Phase A: xp = x@Wx^T + bx (unchanged from round 2; WG-private, ~70 us).
//   Phase B: 2048 steps. Wave wv owns hidden row 16w+wv (Wh row in VGPR/AGPR).
//     Sync protocol redesigned:
//       - publish: one coalesced 32B bf16 store per WG (wave 15)
//       - arrival: atomicAdd tree (16 group counters -> root -> go word)
//       - wait:    wave 0 polls the single go word with s_sleep backoff
//     h broadcast in bf16 (8 KB/WG/step staged to LDS as f32).
//   Phase C: out = sigmoid(hT @ Wo^T + bo).
//
// ws layout (32-bit words):
//   [0..256)    group counters, grp[g] at word g*16 (one 64B line each)
//   [256]       root counter (own line)
//   [320]       go word (own line)
//   [1024,3072) hbuf0: bf16[4096] (h for even-step reads)
//   [3072,5120) hbuf1: bf16[4096]
//   [8192,...)  xp [256][2048][16] f32 (32 MiB)
// words [0,5120) memset to 0 every launch (h0=0, counters=0, deterministic).
// ---------------------------------------------------------------------------

#define T_STEPS  2048
#define INPUT_N  2048
#define HIDDEN_N 4096
#define NWG      256
#define NTHR     1024

typedef float f32x4 __attribute__((ext_vector_type(4)));
typedef unsigned int uint32;

__device__ __forceinline__ float wave_reduce(float v) {
#pragma unroll
  for (int off = 32; off > 0; off >>= 1) v += __shfl_xor(v, off, 64);
  return v;
}

__device__ __forceinline__ float bits_to_f(uint32 u) {
  union { uint32 u; float f; } c; c.u = u; return c.f;
}

__global__ __attribute__((amdgpu_flat_work_group_size(1024, 1024)))
__attribute__((amdgpu_waves_per_eu(4, 4))) void rnn_persistent(
    const float* __restrict__ x,
    const float* __restrict__ wh_w, const float* __restrict__ wh_b,
    const float* __restrict__ wx_w, const float* __restrict__ wx_b,
    const float* __restrict__ wo_w, const float* __restrict__ wo_b,
    float* __restrict__ out, float* __restrict__ ws) {
  const int w    = blockIdx.x;    // owns hidden rows [16w, 16w+16)
  const int tid  = threadIdx.x;
  const int lane = tid & 63;
  const int wv   = tid >> 6;      // wave 0..15

  int*    grp   = (int*)ws;            // grp[g] at word g*16
  int*    root  = (int*)ws + 256;
  int*    go    = (int*)ws + 320;
  uint32* hb0   = (uint32*)(ws + 1024);  // bf16[4096] as 2048 uints
  uint32* hb1   = (uint32*)(ws + 3072);
  float*  xp    = ws + 8192;             // [w][t][16]

  __shared__ float s_h[HIDDEN_N];   // 16 KiB staged h (f32)
  __shared__ float s_hnew[16];

  // ------------------ Phase A: xp (barrier-free, reduce-free) --------------
  {
    const int tq = lane >> 4;        // 0..3
    const int r  = lane & 15;        // row within WG slice
    const float* wrow = wx_w + (size_t)(w * 16 + r) * INPUT_N;
    const float  bA   = wx_b[w * 16 + r];
    for (int g = wv; g < 64; g += 16) {       // 4 groups per wave
      const int t0 = g * 32 + tq;             // t = t0 + 4j, j<8
      f32x4 acc[8];
      const float* xr[8];
#pragma unroll
      for (int j = 0; j < 8; ++j) {
        acc[j] = (f32x4){0.f, 0.f, 0.f, 0.f};
        xr[j]  = x + (size_t)(t0 + 4 * j) * INPUT_N;
      }
      for (int k = 0; k < 512; ++k) {         // 16B granules over K=2048
        f32x4 wq = *(const f32x4*)(wrow + (size_t)k * 4);
#pragma unroll
        for (int j = 0; j < 8; ++j)
          acc[j] += (*(const f32x4*)(xr[j] + (size_t)k * 4)) * wq;
      }
#pragma unroll
      for (int j = 0; j < 8; ++j) {
        float s = acc[j].x + acc[j].y + acc[j].z + acc[j].w + bA;
        xp[((size_t)w * T_STEPS + (t0 + 4 * j)) * 16 + r] = s;
      }
    }
  }
  __syncthreads();   // xp slice complete (WG-private, same CU)

  // ------------------ Phase B: the scan ------------------------------------
  const float* whrow = wh_w + (size_t)(w * 16 + wv) * HIDDEN_N + lane * 4;
  f32x4 W[16];
#pragma unroll
  for (int i = 0; i < 16; ++i) W[i] = *(const f32x4*)(whrow + i * 256);
  const float bB = wh_b[w * 16 + wv];
  const int   mygrp16 = (w >> 4) * 16;   // group counter word index

  for (int t = 0; t < T_STEPS; ++t) {
    // prefetch xp[t][wv] (uniform per wave, WG-private)
    const float xpv = xp[((size_t)w * T_STEPS + t) * 16 + wv];

    // 1) wait for "all h_t published": go >= t (trivially true for t=0)
    if (wv == 0) {
      while (__hip_atomic_load(go, __ATOMIC_RELAXED,
                               __HIP_MEMORY_SCOPE_AGENT) < t)
        __builtin_amdgcn_s_sleep(1);
    }
    __syncthreads();

    // 2) stage h_t (bf16 in L3) -> LDS as f32
    const uint32* hsrc = (t & 1) ? hb1 : hb0;
#pragma unroll
    for (int k = 0; k < 2; ++k) {
      const int idx = tid + k * 1024;            // 0..2047 uints
      uint32 u = __hip_atomic_load(hsrc + idx, __ATOMIC_RELAXED,
                                   __HIP_MEMORY_SCOPE_AGENT);
      float2 p;
      p.x = bits_to_f(u << 16);
      p.y = bits_to_f(u & 0xffff0000u);
      *(float2*)&s_h[2 * idx] = p;
    }
    __syncthreads();

    // 3) full-row dot from LDS against resident W
    f32x4 a0 = {0.f, 0.f, 0.f, 0.f}, a1 = {0.f, 0.f, 0.f, 0.f};
#pragma unroll
    for (int i = 0; i < 16; i += 2) {
      a0 += (*(const f32x4*)&s_h[lane * 4 + i * 256]) * W[i];
      a1 += (*(const f32x4*)&s_h[lane * 4 + (i + 1) * 256]) * W[i + 1];
    }
    float d = wave_reduce(a0.x + a0.y + a0.z + a0.w +
                          a1.x + a1.y + a1.z + a1.w);
    if (lane == 0) s_hnew[wv] = tanhf(d + bB + xpv);
    __syncthreads();

    // 4) wave 15: coalesced bf16 publish + tree arrival
    if (wv == 15) {
      uint32* hdst = (t & 1) ? hb0 : hb1;   // h_{t+1} -> hbuf[(t+1)&1]
      if (lane < 8) {
        __hip_bfloat16 blo = __float2bfloat16(s_hnew[2 * lane]);
        __hip_bfloat16 bhi = __float2bfloat16(s_hnew[2 * lane + 1]);
        uint32 v = (uint32)(*(unsigned short*)&blo) |
                   ((uint32)(*(unsigned short*)&bhi) << 16);
        __hip_atomic_store(hdst + w * 8 + lane, v, __ATOMIC_RELAXED,
                           __HIP_MEMORY_SCOPE_AGENT);
      }
      asm volatile("s_waitcnt vmcnt(0)" ::: "memory");  // h landed at L3
      if (lane == 0) {
        int old = __hip_atomic_fetch_add(&grp[mygrp16], 1, __ATOMIC_RELAXED,
                                         __HIP_MEMORY_SCOPE_AGENT);
        if (old + 1 == 16 * (t + 1)) {          // last of my 16-WG group
          int ro = __hip_atomic_fetch_add(root, 1, __ATOMIC_RELAXED,
                                          __HIP_MEMORY_SCOPE_AGENT);
          if (ro + 1 == 16 * (t + 1)) {         // last group
            __hip_atomic_store(go, t + 1, __ATOMIC_RELAXED,
                               __HIP_MEMORY_SCOPE_AGENT);
          }
        }
      }
    }
  }

  // ------------------ Phase C: output --------------------------------------
  if (wv == 0) {
    while (__hip_atomic_load(go, __ATOMIC_RELAXED,
                             __HIP_MEMORY_SCOPE_AGENT) < T_STEPS)
      __builtin_amdgcn_s_sleep(1);
  }
  __syncthreads();
  // h_T is in hbuf[2048&1] = hb0
#pragma unroll
  for (int k = 0; k < 2; ++k) {
    const int idx = tid + k * 1024;
    uint32 u = __hip_atomic_load(hb0 + idx, __ATOMIC_RELAXED,
                                 __HIP_MEMORY_SCOPE_AGENT);
    float2 p;
    p.x = bits_to_f(u << 16);
    p.y = bits_to_f(u & 0xffff0000u);
    *(float2*)&s_h[2 * idx] = p;
  }
  __syncthreads();
  if (wv < 8) {
    const int o = w * 8 + wv;
    const float* worow = wo_w + (size_t)o * HIDDEN_N + lane * 4;
    f32x4 acc = {0.f, 0.f, 0.f, 0.f};
#pragma unroll
    for (int k = 0; k < 16; ++k)
      acc += (*(const f32x4*)(worow + k * 256)) *
             (*(const f32x4*)&s_h[lane * 4 + k * 256]);
    float s = wave_reduce(acc.x + acc.y + acc.z + acc.w);
    if (lane == 0) {
      float z = s + wo_b[o];
      out[o] = 1.f / (1.f + expf(-z));
    }
  }
}

extern "C" void kernel_launch(void* const* d_in, const int* in_sizes, int n_in,
                              void* d_out, int out_size, void* d_ws,
                              size_t ws_size, hipStream_t stream) {
  const float* x    = (const float*)d_in[0];
  const float* wh_w = (const float*)d_in[1];
  const float* wh_b = (const float*)d_in[2];
  const float* wx_w = (const float*)d_in[3];
  const float* wx_b = (const float*)d_in[4];
  const float* wo_w = (const float*)d_in[5];
  const float* wo_b = (const float*)d_in[6];
  float* out = (float*)d_out;
  float* ws  = (float*)d_ws;

  // counters + go + h double-buffer zeroed every call (deterministic replay)
  hipMemsetAsync(d_ws, 0, 5120 * 4, stream);

  hipLaunchKernelGGL(rnn_persistent, dim3(NWG), dim3(NTHR), 0, stream,
                     x, wh_w, wh_b, wx_w, wx_b, wo_w, wo_b, out, ws);
}